// Round 2
// baseline (274.545 us; speedup 1.0000x reference)
//
#include <hip/hip_runtime.h>

#define BB 128
#define TT 4096
#define LL 43
#define CC 46             // L + 3
#define CHUNK 256
#define NC (TT / CHUNK)   // 16 chunks
#define TPB 256
#define NBLK (NC * BB)    // 2048
#define NEGF (-1e30f)
#define L2E 1.44269504088896340736f
#define LN2 0.69314718055994530942f

// logaddexp in log2 domain
__device__ __forceinline__ float la2(float x, float y) {
    float mx = fmaxf(x, y), mn = fminf(x, y);
    return mx + log2f(1.0f + exp2f(mn - mx));
}

// ws layout: res[B][NC][8] floats (65536 B), then unsigned counter at +65536
__global__ __launch_bounds__(TPB) void crf_fused(
    const float* __restrict__ lp, const float* __restrict__ dp,
    const int* __restrict__ lens, const int* __restrict__ labels,
    float* __restrict__ res, unsigned* __restrict__ cnt,
    float* __restrict__ out) {
    __shared__ float tile[CHUNK * CC];   // 47104 B
    __shared__ float2 pp[LL];            // (p0[j], p1[j])
    __shared__ float sc[4];              // pO, s0I*L2E, s1I*L2E, sfin*L2E
    __shared__ float wres[TPB / 64][5];
    __shared__ float part[4];
    __shared__ int flagsh;

    int b = blockIdx.y, c = blockIdx.x;
    int t0 = c * CHUNK;
    int len = lens[b];
    bool masked = (t0 >= len);
    int tid = threadIdx.x;

    // ---- prep (wave 0, redundant per block; ~100 cycles) ----
    if (tid < 64) {
        int lane = tid;
        float x0 = (lane < CC) ? dp[lane] : NEGF;
        float x1 = (lane < LL + 1) ? dp[CC + lane] : NEGF;
        float mx0 = x0, mx1 = x1;
        #pragma unroll
        for (int m = 1; m < 64; m <<= 1) {
            mx0 = fmaxf(mx0, __shfl_xor(mx0, m));
            mx1 = fmaxf(mx1, __shfl_xor(mx1, m));
        }
        float e0 = (lane < CC) ? expf(x0 - mx0) : 0.0f;
        float e1 = (lane < LL + 1) ? expf(x1 - mx1) : 0.0f;
        float s0 = e0, s1 = e1;
        #pragma unroll
        for (int m = 1; m < 64; m <<= 1) {
            s0 += __shfl_xor(s0, m);
            s1 += __shfl_xor(s1, m);
        }
        float g0 = x0 - mx0 - logf(s0);
        float g1 = x1 - mx1 - logf(s1);
        if (lane >= 1 && lane <= LL) { pp[lane - 1].x = expf(g0); pp[lane - 1].y = expf(g1); }
        if (lane == 0) { sc[0] = expf(g0); sc[2] = g1 * L2E; }
        if (lane == LL + 1) sc[1] = g0 * L2E;
        if (lane == LL + 2) sc[3] = g0 * L2E;
    }

    int t = t0 + tid;
    int lab = labels[b * TT + t];   // issue early, used post-barrier

    // ---- stage 256x46 f32 tile, coalesced float4 (skip if fully masked) ----
    if (!masked) {
        const float4* src = (const float4*)(lp + (size_t)(b * TT + t0) * CC);
        float4* dst = (float4*)tile;
        #pragma unroll 4
        for (int i = tid; i < CHUNK * CC / 4; i += TPB) dst[i] = src[i];
    }
    __syncthreads();

    // ---- per-timestep 2x2 log-semiring matrix ----
    const float* vr = tile + tid * CC;   // 8B-aligned (46 floats/row)
    float m00, m01, m10, m11, tok;
    {
        const float2* vr2 = (const float2*)vr;
        float2 c01 = vr2[0];                 // cols 0,1
        float2 c23 = vr2[1];                 // cols 2,3
        float w1 = exp2f(L2E * c01.y);
        float v2s = L2E * c23.x;
        float dot0 = sc[0] * w1;             // pO * P(col1)
        float dot1 = 0.f;
        {
            float w = exp2f(L2E * c23.y);    // label j=0
            float2 p = pp[0];
            dot0 = fmaf(p.x, w, dot0);
            dot1 = fmaf(p.y, w, dot1);
        }
        #pragma unroll
        for (int k = 2; k <= 22; ++k) {      // cols 2k,2k+1 -> labels j=2k-3,2k-2
            float2 v = vr2[k];
            float wa = exp2f(L2E * v.x), wb = exp2f(L2E * v.y);
            float2 pa = pp[2 * k - 3], pb = pp[2 * k - 2];
            dot0 = fmaf(pa.x, wa, dot0); dot1 = fmaf(pa.y, wa, dot1);
            dot0 = fmaf(pb.x, wb, dot0); dot1 = fmaf(pb.y, wb, dot1);
        }
        m00 = log2f(dot0);
        m01 = log2f(dot1);
        m10 = sc[1] + v2s;
        m11 = sc[2] + v2s;
        tok = vr[lab];                       // natural-log value for numerator
    }
    if (t >= len) { m00 = 0.f; m01 = NEGF; m10 = NEGF; m11 = 0.f; tok = 0.f; }

    // ---- order-preserving xor-tree composition across the wave ----
    int lane = tid & 63;
    #pragma unroll
    for (int m = 1; m < 64; m <<= 1) {
        float p00 = __shfl_xor(m00, m), p01 = __shfl_xor(m01, m);
        float p10 = __shfl_xor(m10, m), p11 = __shfl_xor(m11, m);
        bool up = (lane & m) != 0;           // my segment is LATER in time
        float a00 = up ? m00 : p00, a01 = up ? m01 : p01;
        float a10 = up ? m10 : p10, a11 = up ? m11 : p11;
        float b00 = up ? p00 : m00, b01 = up ? p01 : m01;
        float b10 = up ? p10 : m10, b11 = up ? p11 : m11;
        m00 = la2(a00 + b00, a01 + b10);
        m01 = la2(a00 + b01, a01 + b11);
        m10 = la2(a10 + b00, a11 + b10);
        m11 = la2(a10 + b01, a11 + b11);
        tok += __shfl_xor(tok, m);
    }
    if (lane == 0) {
        int w = tid >> 6;
        wres[w][0] = m00; wres[w][1] = m01; wres[w][2] = m10; wres[w][3] = m11; wres[w][4] = tok;
    }
    __syncthreads();

    // ---- thread 0: combine 4 wave results, publish, bump counter ----
    if (tid == 0) {
        float c00 = wres[0][0], c01 = wres[0][1], c10 = wres[0][2], c11 = wres[0][3];
        float num = wres[0][4];
        #pragma unroll
        for (int w = 1; w < TPB / 64; ++w) {
            float a00 = wres[w][0], a01 = wres[w][1], a10 = wres[w][2], a11 = wres[w][3];
            float n00 = la2(a00 + c00, a01 + c10);
            float n01 = la2(a00 + c01, a01 + c11);
            float n10 = la2(a10 + c00, a11 + c10);
            float n11 = la2(a10 + c01, a11 + c11);
            c00 = n00; c01 = n01; c10 = n10; c11 = n11;
            num += wres[w][4];
        }
        float* r = res + (b * NC + c) * 8;
        __hip_atomic_store(r + 0, c00, __ATOMIC_RELAXED, __HIP_MEMORY_SCOPE_AGENT);
        __hip_atomic_store(r + 1, c01, __ATOMIC_RELAXED, __HIP_MEMORY_SCOPE_AGENT);
        __hip_atomic_store(r + 2, c10, __ATOMIC_RELAXED, __HIP_MEMORY_SCOPE_AGENT);
        __hip_atomic_store(r + 3, c11, __ATOMIC_RELAXED, __HIP_MEMORY_SCOPE_AGENT);
        __hip_atomic_store(r + 4, num, __ATOMIC_RELAXED, __HIP_MEMORY_SCOPE_AGENT);
        __threadfence();   // release our res slot device-wide
        unsigned old = __hip_atomic_fetch_add(cnt, 1u, __ATOMIC_ACQ_REL, __HIP_MEMORY_SCOPE_AGENT);
        flagsh = (old == NBLK - 1) ? 1 : 0;
    }
    __syncthreads();

    // ---- last block standing does the final reduction (block-uniform branch) ----
    if (flagsh) {
        __threadfence();   // acquire all res slots
        float val = 0.f;
        if (tid < BB) {
            float a0 = 0.f, a1 = NEGF, num = 0.f;
            #pragma unroll 4
            for (int cc = 0; cc < NC; ++cc) {
                const float* r = res + (tid * NC + cc) * 8;
                float r0 = __hip_atomic_load(r + 0, __ATOMIC_RELAXED, __HIP_MEMORY_SCOPE_AGENT);
                float r1 = __hip_atomic_load(r + 1, __ATOMIC_RELAXED, __HIP_MEMORY_SCOPE_AGENT);
                float r2 = __hip_atomic_load(r + 2, __ATOMIC_RELAXED, __HIP_MEMORY_SCOPE_AGENT);
                float r3 = __hip_atomic_load(r + 3, __ATOMIC_RELAXED, __HIP_MEMORY_SCOPE_AGENT);
                float r4 = __hip_atomic_load(r + 4, __ATOMIC_RELAXED, __HIP_MEMORY_SCOPE_AGENT);
                float n0 = la2(r0 + a0, r1 + a1);
                float n1 = la2(r2 + a0, r3 + a1);
                a0 = n0; a1 = n1; num += r4;
            }
            val = num - (a0 + sc[3]) * LN2;   // log2 -> natural log
        }
        #pragma unroll
        for (int m = 1; m < 64; m <<= 1) val += __shfl_xor(val, m);
        if ((tid & 63) == 0) part[tid >> 6] = val;
        __syncthreads();
        if (tid == 0) out[0] = part[0] + part[1] + part[2] + part[3];
    }
}

extern "C" void kernel_launch(void* const* d_in, const int* in_sizes, int n_in,
                              void* d_out, int out_size, void* d_ws, size_t ws_size,
                              hipStream_t stream) {
    const float* lp = (const float*)d_in[0];      // (B,T,C) f32
    const float* dp = (const float*)d_in[1];      // (2L+4,) f32
    const int* lens = (const int*)d_in[2];        // (B,) i32
    const int* labels = (const int*)d_in[3];      // (B,T) i32
    float* out = (float*)d_out;
    float* res = (float*)d_ws;                    // B*NC*8 floats = 65536 B
    unsigned* cnt = (unsigned*)((char*)d_ws + 65536);

    hipMemsetAsync(cnt, 0, sizeof(unsigned), stream);
    hipLaunchKernelGGL(crf_fused, dim3(NC, BB), dim3(TPB), 0, stream,
                       lp, dp, lens, labels, res, cnt, out);
}

// Round 3
// 154.615 us; speedup vs baseline: 1.7757x; 1.7757x over previous
//
#include <hip/hip_runtime.h>

#define BB 128
#define TT 4096
#define LL 43
#define CC 46             // L + 3
#define CHUNK 256
#define NC (TT / CHUNK)   // 16 chunks
#define TPB 256
#define NEGF (-1e30f)
#define L2E 1.44269504088896340736f
#define LN2 0.69314718055994530942f

// logaddexp in log2 domain
__device__ __forceinline__ float la2(float x, float y) {
    float mx = fmaxf(x, y), mn = fminf(x, y);
    return mx + log2f(1.0f + exp2f(mn - mx));
}

// ws layout: res[B][NC][8] floats (65536 B)
__global__ __launch_bounds__(TPB) void crf_chunk(
    const float* __restrict__ lp, const float* __restrict__ dp,
    const int* __restrict__ lens, const int* __restrict__ labels,
    float* __restrict__ res) {
    __shared__ float tile[CHUNK * CC];   // 47104 B
    __shared__ float2 pp[LL];            // (p0[j], p1[j])
    __shared__ float sc[4];              // pO, s0I*L2E, s1I*L2E, sfin*L2E
    __shared__ float wres[TPB / 64][5];

    int b = blockIdx.y, c = blockIdx.x;
    int t0 = c * CHUNK;
    int len = lens[b];
    int tid = threadIdx.x;
    float* r = res + (b * NC + c) * 8;

    if (t0 >= len) {   // fully masked chunk: identity, no HBM traffic
        if (tid == 0) { r[0] = 0.f; r[1] = NEGF; r[2] = NEGF; r[3] = 0.f; r[4] = 0.f; }
        return;
    }

    // ---- async global->LDS staging: 46 segments x 1024B, fire-and-forget ----
    {
        int wv = tid >> 6, ln = tid & 63;
        const float* gsrc = lp + (size_t)(b * TT + t0) * CC;
        for (int s = wv; s < CC; s += TPB / 64) {
            const float* g = gsrc + s * 256 + ln * 4;    // per-lane, coalesced 16B
            float* l = tile + s * 256;                   // wave-uniform base (+lane*16 implicit)
            __builtin_amdgcn_global_load_lds(
                (const __attribute__((address_space(1))) void*)g,
                (__attribute__((address_space(3))) void*)l, 16, 0, 0);
        }
    }

    // ---- prep (wave 0, redundant per block; overlaps with staging) ----
    if (tid < 64) {
        int lane = tid;
        float x0 = (lane < CC) ? dp[lane] : NEGF;
        float x1 = (lane < LL + 1) ? dp[CC + lane] : NEGF;
        float mx0 = x0, mx1 = x1;
        #pragma unroll
        for (int m = 1; m < 64; m <<= 1) {
            mx0 = fmaxf(mx0, __shfl_xor(mx0, m));
            mx1 = fmaxf(mx1, __shfl_xor(mx1, m));
        }
        float e0 = (lane < CC) ? expf(x0 - mx0) : 0.0f;
        float e1 = (lane < LL + 1) ? expf(x1 - mx1) : 0.0f;
        float s0 = e0, s1 = e1;
        #pragma unroll
        for (int m = 1; m < 64; m <<= 1) {
            s0 += __shfl_xor(s0, m);
            s1 += __shfl_xor(s1, m);
        }
        float g0 = x0 - mx0 - logf(s0);
        float g1 = x1 - mx1 - logf(s1);
        if (lane >= 1 && lane <= LL) { pp[lane - 1].x = expf(g0); pp[lane - 1].y = expf(g1); }
        if (lane == 0) { sc[0] = expf(g0); sc[2] = g1 * L2E; }
        if (lane == LL + 1) sc[1] = g0 * L2E;
        if (lane == LL + 2) sc[3] = g0 * L2E;
    }

    int t = t0 + tid;
    int lab = labels[b * TT + t];   // coalesced; overlaps staging drain
    __syncthreads();                // drains vmcnt (global_load_lds) + lgkmcnt

    // ---- per-timestep 2x2 log-semiring matrix ----
    const float* vr = tile + tid * CC;   // 8B-aligned (46 floats/row)
    float m00, m01, m10, m11, tok;
    {
        const float2* vr2 = (const float2*)vr;
        float2 c01 = vr2[0];                 // cols 0,1
        float2 c23 = vr2[1];                 // cols 2,3
        float w1 = exp2f(L2E * c01.y);
        float v2s = L2E * c23.x;
        float dot0 = sc[0] * w1;             // pO * P(col1)
        float dot1 = 0.f;
        {
            float w = exp2f(L2E * c23.y);    // label j=0
            float2 p = pp[0];
            dot0 = fmaf(p.x, w, dot0);
            dot1 = fmaf(p.y, w, dot1);
        }
        #pragma unroll
        for (int k = 2; k <= 22; ++k) {      // cols 2k,2k+1 -> labels j=2k-3,2k-2
            float2 v = vr2[k];
            float wa = exp2f(L2E * v.x), wb = exp2f(L2E * v.y);
            float2 pa = pp[2 * k - 3], pb = pp[2 * k - 2];
            dot0 = fmaf(pa.x, wa, dot0); dot1 = fmaf(pa.y, wa, dot1);
            dot0 = fmaf(pb.x, wb, dot0); dot1 = fmaf(pb.y, wb, dot1);
        }
        m00 = log2f(dot0);
        m01 = log2f(dot1);
        m10 = sc[1] + v2s;
        m11 = sc[2] + v2s;
        tok = vr[lab];                       // natural-log value for numerator
    }
    if (t >= len) { m00 = 0.f; m01 = NEGF; m10 = NEGF; m11 = 0.f; tok = 0.f; }

    // ---- order-preserving xor-tree composition across the wave ----
    int lane = tid & 63;
    #pragma unroll
    for (int m = 1; m < 64; m <<= 1) {
        float p00 = __shfl_xor(m00, m), p01 = __shfl_xor(m01, m);
        float p10 = __shfl_xor(m10, m), p11 = __shfl_xor(m11, m);
        bool up = (lane & m) != 0;           // my segment is LATER in time
        float a00 = up ? m00 : p00, a01 = up ? m01 : p01;
        float a10 = up ? m10 : p10, a11 = up ? m11 : p11;
        float b00 = up ? p00 : m00, b01 = up ? p01 : m01;
        float b10 = up ? p10 : m10, b11 = up ? p11 : m11;
        m00 = la2(a00 + b00, a01 + b10);
        m01 = la2(a00 + b01, a01 + b11);
        m10 = la2(a10 + b00, a11 + b10);
        m11 = la2(a10 + b01, a11 + b11);
        tok += __shfl_xor(tok, m);
    }
    if (lane == 0) {
        int w = tid >> 6;
        wres[w][0] = m00; wres[w][1] = m01; wres[w][2] = m10; wres[w][3] = m11; wres[w][4] = tok;
    }
    __syncthreads();

    // ---- thread 0: combine 4 wave results, store ----
    if (tid == 0) {
        float c00 = wres[0][0], c01 = wres[0][1], c10 = wres[0][2], c11 = wres[0][3];
        float num = wres[0][4];
        #pragma unroll
        for (int w = 1; w < TPB / 64; ++w) {
            float a00 = wres[w][0], a01 = wres[w][1], a10 = wres[w][2], a11 = wres[w][3];
            float n00 = la2(a00 + c00, a01 + c10);
            float n01 = la2(a00 + c01, a01 + c11);
            float n10 = la2(a10 + c00, a11 + c10);
            float n11 = la2(a10 + c01, a11 + c11);
            c00 = n00; c01 = n01; c10 = n10; c11 = n11;
            num += wres[w][4];
        }
        r[0] = c00; r[1] = c01; r[2] = c10; r[3] = c11; r[4] = num;
    }
}

__global__ void crf_final(const float* __restrict__ dp, const float* __restrict__ res,
                          float* __restrict__ out) {
    __shared__ float sfin2sh;
    __shared__ float part[2];
    int tid = threadIdx.x;   // 128 threads
    if (tid < 64) {          // recompute sfin = log_softmax(dp[:C])[L+2], in log2
        float x0 = (tid < CC) ? dp[tid] : NEGF;
        float mx0 = x0;
        #pragma unroll
        for (int m = 1; m < 64; m <<= 1) mx0 = fmaxf(mx0, __shfl_xor(mx0, m));
        float e0 = (tid < CC) ? expf(x0 - mx0) : 0.0f;
        float s0 = e0;
        #pragma unroll
        for (int m = 1; m < 64; m <<= 1) s0 += __shfl_xor(s0, m);
        if (tid == LL + 2) sfin2sh = (x0 - mx0 - logf(s0)) * L2E;
    }
    __syncthreads();
    float a0 = 0.f, a1 = NEGF, num = 0.f;
    #pragma unroll 4
    for (int c = 0; c < NC; ++c) {
        const float* r = res + (tid * NC + c) * 8;
        float n0 = la2(r[0] + a0, r[1] + a1);
        float n1 = la2(r[2] + a0, r[3] + a1);
        a0 = n0; a1 = n1; num += r[4];
    }
    float val = num - (a0 + sfin2sh) * LN2;   // log2 -> natural log
    #pragma unroll
    for (int m = 1; m < 64; m <<= 1) val += __shfl_xor(val, m);
    if ((tid & 63) == 0) part[tid >> 6] = val;
    __syncthreads();
    if (tid == 0) out[0] = part[0] + part[1];
}

extern "C" void kernel_launch(void* const* d_in, const int* in_sizes, int n_in,
                              void* d_out, int out_size, void* d_ws, size_t ws_size,
                              hipStream_t stream) {
    const float* lp = (const float*)d_in[0];      // (B,T,C) f32
    const float* dp = (const float*)d_in[1];      // (2L+4,) f32
    const int* lens = (const int*)d_in[2];        // (B,) i32
    const int* labels = (const int*)d_in[3];      // (B,T) i32
    float* out = (float*)d_out;
    float* res = (float*)d_ws;                    // B*NC*8 floats = 65536 B

    hipLaunchKernelGGL(crf_chunk, dim3(NC, BB), dim3(TPB), 0, stream,
                       lp, dp, lens, labels, res);
    hipLaunchKernelGGL(crf_final, dim3(1), dim3(128), 0, stream, dp, res, out);
}